// Round 1
// baseline (1369.859 us; speedup 1.0000x reference)
//
#include <hip/hip_runtime.h>

#define FEATS 40960
#define ACC 512
#define NBATCH 4096
#define CAP 192

__device__ __forceinline__ float screlu_f(float v) {
  v = fminf(fmaxf(v, 0.0f), 1.0f);
  return v * v;
}

// Transpose ft_w (512, FEATS) -> wt (FEATS, 512) so per-feature rows are contiguous.
__global__ __launch_bounds__(256) void transpose_ftw(const float* __restrict__ w,
                                                     float* __restrict__ wt) {
  __shared__ float tile[64][65];
  const int f0 = blockIdx.x * 64;
  const int o0 = blockIdx.y * 64;
  const int tx = threadIdx.x & 63;
  const int ty = threadIdx.x >> 6;
#pragma unroll
  for (int i = 0; i < 16; ++i) {
    const int o = ty * 16 + i;
    tile[o][tx] = w[(size_t)(o0 + o) * FEATS + (f0 + tx)];
  }
  __syncthreads();
#pragma unroll
  for (int i = 0; i < 16; ++i) {
    const int f = ty * 16 + i;
    wt[(size_t)(f0 + f) * ACC + (o0 + tx)] = tile[tx][f];
  }
}

// One block per batch row. 256 threads.
__global__ __launch_bounds__(256) void nnue_fused(
    const float* __restrict__ wfeat, const float* __restrict__ bfeat,
    const unsigned char* __restrict__ stm8,
    const float* __restrict__ wt, const float* __restrict__ ftb,
    const float* __restrict__ l1w, const float* __restrict__ l1b,
    const float* __restrict__ l2w, const float* __restrict__ l2b,
    const float* __restrict__ ow, const float* __restrict__ ob,
    float* __restrict__ out)
{
  __shared__ int wcnt, bcnt, u8flag;
  __shared__ int widx[CAP], bidx[CAP];
  __shared__ __align__(16) float x[1024];
  __shared__ float part[8][32];
  __shared__ float v1[32];

  const int t = threadIdx.x;
  const int row = blockIdx.x;

  if (t == 0) { wcnt = 0; bcnt = 0; u8flag = 0; }
  __syncthreads();

  // stm storage-format probe: if bool array is int32-encoded, bytes at 4k+1 are all 0.
  if (stm8[4 * t + 1] != 0) u8flag = 1;

  // ---- scan both feature rows for nonzeros (values are exactly 0.0f/1.0f) ----
  const uint4* w4 = (const uint4*)(wfeat + (size_t)row * FEATS);
  const uint4* b4 = (const uint4*)(bfeat + (size_t)row * FEATS);
  for (int i = t; i < FEATS / 4; i += 256) {
    const uint4 a = w4[i];
    if (a.x | a.y | a.z | a.w) {
      if (a.x) { int p = atomicAdd(&wcnt, 1); if (p < CAP) widx[p] = 4 * i + 0; }
      if (a.y) { int p = atomicAdd(&wcnt, 1); if (p < CAP) widx[p] = 4 * i + 1; }
      if (a.z) { int p = atomicAdd(&wcnt, 1); if (p < CAP) widx[p] = 4 * i + 2; }
      if (a.w) { int p = atomicAdd(&wcnt, 1); if (p < CAP) widx[p] = 4 * i + 3; }
    }
    const uint4 b = b4[i];
    if (b.x | b.y | b.z | b.w) {
      if (b.x) { int p = atomicAdd(&bcnt, 1); if (p < CAP) bidx[p] = 4 * i + 0; }
      if (b.y) { int p = atomicAdd(&bcnt, 1); if (p < CAP) bidx[p] = 4 * i + 1; }
      if (b.z) { int p = atomicAdd(&bcnt, 1); if (p < CAP) bidx[p] = 4 * i + 2; }
      if (b.w) { int p = atomicAdd(&bcnt, 1); if (p < CAP) bidx[p] = 4 * i + 3; }
    }
  }
  __syncthreads();

  // ---- gather-accumulate transposed ft_w rows; each thread owns acc elems 2t, 2t+1 ----
  const int nw = min(wcnt, CAP);
  const int nb = min(bcnt, CAP);
  float accwx = 0.f, accwy = 0.f, accbx = 0.f, accby = 0.f;
  const float2* wt2 = (const float2*)wt;
  for (int i = 0; i < nw; ++i) {
    const float2 v = wt2[(size_t)widx[i] * (ACC / 2) + t];
    accwx += v.x; accwy += v.y;
  }
  for (int i = 0; i < nb; ++i) {
    const float2 v = wt2[(size_t)bidx[i] * (ACC / 2) + t];
    accbx += v.x; accby += v.y;
  }
  const float2 bias = ((const float2*)ftb)[t];
  accwx = screlu_f(accwx + bias.x); accwy = screlu_f(accwy + bias.y);
  accbx = screlu_f(accbx + bias.x); accby = screlu_f(accby + bias.y);

  // ---- stm select into x[1024]: first half = stm ? black : white ----
  const int stm = (u8flag != 0) ? (int)stm8[row] : ((const int*)stm8)[row];
  const int woff = stm ? 512 : 0;
  const int boff = 512 - woff;
  x[woff + 2 * t]     = accwx;
  x[woff + 2 * t + 1] = accwy;
  x[boff + 2 * t]     = accbx;
  x[boff + 2 * t + 1] = accby;
  __syncthreads();

  // ---- l1: 32 outputs x dot-1024; thread (o = t&31, chunk c = t>>5) ----
  const int o = t & 31, c = t >> 5;
  const float4* lw4 = (const float4*)(l1w + (size_t)o * 1024 + c * 128);
  const float4* x4  = (const float4*)(x) + c * 32;
  float s = 0.f;
#pragma unroll
  for (int i = 0; i < 32; ++i) {
    const float4 wv = lw4[i];
    const float4 xv = x4[i];
    s += wv.x * xv.x + wv.y * xv.y + wv.z * xv.z + wv.w * xv.w;
  }
  part[c][o] = s;
  __syncthreads();

  if (t < 32) {
    float r = l1b[t];
#pragma unroll
    for (int cc = 0; cc < 8; ++cc) r += part[cc][t];
    v1[t] = screlu_f(r);
  }
  __syncthreads();

  // ---- l2 + out head, lanes 0..31 of wave 0 ----
  if (t < 32) {
    float r = l2b[t];
#pragma unroll
    for (int k = 0; k < 32; ++k) r += l2w[t * 32 + k] * v1[k];
    float res = screlu_f(r) * ow[t];
#pragma unroll
    for (int off = 16; off; off >>= 1) res += __shfl_down(res, off, 32);
    if (t == 0) out[row] = res + ob[0];
  }
}

extern "C" void kernel_launch(void* const* d_in, const int* in_sizes, int n_in,
                              void* d_out, int out_size, void* d_ws, size_t ws_size,
                              hipStream_t stream) {
  const float* wfeat = (const float*)d_in[0];
  const float* bfeat = (const float*)d_in[1];
  const unsigned char* stm = (const unsigned char*)d_in[2];
  const float* ftw = (const float*)d_in[3];
  const float* ftb = (const float*)d_in[4];
  const float* l1w = (const float*)d_in[5];
  const float* l1b = (const float*)d_in[6];
  const float* l2w = (const float*)d_in[7];
  const float* l2b = (const float*)d_in[8];
  const float* ow  = (const float*)d_in[9];
  const float* ob  = (const float*)d_in[10];
  float* out = (float*)d_out;
  float* wt  = (float*)d_ws;  // 40960*512*4 = 84 MB transposed ft_w

  dim3 tgrid(FEATS / 64, ACC / 64);
  transpose_ftw<<<tgrid, dim3(256), 0, stream>>>(ftw, wt);
  nnue_fused<<<dim3(NBATCH), dim3(256), 0, stream>>>(
      wfeat, bfeat, stm, wt, ftb, l1w, l1b, l2w, l2b, ow, ob, out);
}